// Round 5
// baseline (312.368 us; speedup 1.0000x reference)
//
#include <hip/hip_runtime.h>

// StepConditionalLoReFT: out = h + Rn^T (W h + b - Rn h) per step s.
// All tensors FP32 (per reference). B=8 S=50 T=77 D=1024 r=16.
//
// Two kernels:
//  1) loreft_prep (50 blocks): Rn = R/max(||R||,eps), M = W - Rn -> bf16 in
//     workspace: Mg[s][r][d] (GEMM1 B-frag order), Rg[s][d][r] (GEMM2 A-frag
//     order). 3.3 MB total -> L2-resident for the main kernel.
//  2) loreft_main (grid 78 x 50, 128 thr = 2 waves, NO LDS, NO barriers):
//     blockIdx.x = tile*2 + half (halves adjacent in dispatch order -> share
//     the h tile via L2/L3). Each block runs full GEMM1 for its 16-token
//     tile; each wave computes a QUARTER of the GEMM2 d-range
//     (dt0 = (half*2+wvi)*16). 7800 waves (~30/CU) doubles round-2's
//     concurrency, which was the BW limiter (29.6% occupancy @ 2.5 TB/s).
//     Block shape kept at 128/(128,4) -- identical launch config to the
//     round-2 kernel that ran cleanly.

typedef __attribute__((ext_vector_type(8))) short short8;
typedef __attribute__((ext_vector_type(4))) float floatx4;

__device__ __forceinline__ short f2bf(float f) {
  unsigned u = __float_as_uint(f);
  u += 0x7fffu + ((u >> 16) & 1u);   // round-to-nearest-even
  return (short)(u >> 16);
}

#define S_ 50
#define T_ 77
#define NTOK 616   // B*T tokens per step s

// ================= prep kernel =================
__global__ __launch_bounds__(256) void loreft_prep(
    const float* __restrict__ RG, const float* __restrict__ WG,
    short* __restrict__ Mg, short* __restrict__ Rg) {
  __shared__ float RnL[16][1024];
  const int s = blockIdx.x;
  const int tid = threadIdx.x;
  const int lane = tid & 63;
  const int wvi = tid >> 6;

#pragma unroll
  for (int rr = 0; rr < 4; ++rr) {
    const int r = wvi * 4 + rr;
    const floatx4* Rrow = (const floatx4*)(RG + (size_t)((s * 16 + r) << 10));
    const floatx4* Wrow = (const floatx4*)(WG + (size_t)((s * 16 + r) << 10));
    floatx4 rv0 = Rrow[lane * 4 + 0];
    floatx4 rv1 = Rrow[lane * 4 + 1];
    floatx4 rv2 = Rrow[lane * 4 + 2];
    floatx4 rv3 = Rrow[lane * 4 + 3];
    float ss = 0.f;
#pragma unroll
    for (int j = 0; j < 4; ++j)
      ss += rv0[j] * rv0[j] + rv1[j] * rv1[j] + rv2[j] * rv2[j] + rv3[j] * rv3[j];
#pragma unroll
    for (int m = 1; m < 64; m <<= 1) ss += __shfl_xor(ss, m);
    const float inv = 1.0f / fmaxf(sqrtf(ss), 1e-12f);

    floatx4 wa0 = Wrow[lane * 4 + 0];
    floatx4 wa1 = Wrow[lane * 4 + 1];
    floatx4 wa2 = Wrow[lane * 4 + 2];
    floatx4 wa3 = Wrow[lane * 4 + 3];
    float rn[16];
    short8 m0, m1;
#pragma unroll
    for (int j = 0; j < 4; ++j) {
      rn[j]      = rv0[j] * inv;  m0[j]     = f2bf(wa0[j] - rn[j]);
      rn[4 + j]  = rv1[j] * inv;  m0[4 + j] = f2bf(wa1[j] - rn[4 + j]);
      rn[8 + j]  = rv2[j] * inv;  m1[j]     = f2bf(wa2[j] - rn[8 + j]);
      rn[12 + j] = rv3[j] * inv;  m1[4 + j] = f2bf(wa3[j] - rn[12 + j]);
    }
    // Mg[s][r][d] row-major bf16, lane covers d = lane*16 .. +15
    short* mdst = Mg + (size_t)(s * 16 + r) * 1024 + lane * 16;
    *(short8*)mdst = m0;
    *(short8*)(mdst + 8) = m1;
#pragma unroll
    for (int jj = 0; jj < 16; ++jj) RnL[r][lane * 16 + jj] = rn[jj];
  }
  __syncthreads();

  // Rg[s][d][r]: thread handles d = dd*256 + tid, writes 16 r-values (32 B)
#pragma unroll
  for (int dd = 0; dd < 4; ++dd) {
    const int d = dd * 256 + tid;
    short8 lo8, hi8;
#pragma unroll
    for (int rj = 0; rj < 8; ++rj) {
      lo8[rj] = f2bf(RnL[rj][d]);
      hi8[rj] = f2bf(RnL[rj + 8][d]);
    }
    short* dst = Rg + ((size_t)s * 1024 + d) * 16;
    *(short8*)dst = lo8;
    *(short8*)(dst + 8) = hi8;
  }
}

// ===== main kernel: 2 waves/block, d-range split across 2 blocks =========
__global__ __launch_bounds__(128, 4) void loreft_main(
    const float* __restrict__ hG, const float* __restrict__ bG,
    const short* __restrict__ Mg, const short* __restrict__ Rg,
    float* __restrict__ outG) {
  const int tid = threadIdx.x;
  const int lane = tid & 63;
  const int wvi = tid >> 6;       // wave 0..1, fully independent
  const int m16 = lane & 15;
  const int quad = lane >> 4;
  const int s = blockIdx.y;
  const int tile = blockIdx.x >> 1;
  const int half = blockIdx.x & 1;

  const int tokbase = tile * 16;                // 39 tiles cover 616 tokens
  int tokA = tokbase + m16; if (tokA > NTOK - 1) tokA = NTOK - 1;
  const int bb1 = tokA / T_;
  const int tt1 = tokA - bb1 * T_;
  const size_t rowoff = ((size_t)((bb1 * S_ + s) * T_ + tt1)) << 10;
  const float* hrow = hG + rowoff;
  const floatx4* hrow4 = (const floatx4*)hrow;
  // GEMM1 B-frag: lane (quad,m16) needs M[r=m16][k = kb*32 + quad*8 + j]
  const short* mrow = Mg + (size_t)(s * 16 + m16) * 1024 + quad * 8;

  // ---------- GEMM1: c[tok, r] = H M^T, 4-deep staged pipeline ----------
  // (duplicated across waves/half-blocks; h lines are L2/L3 hits after
  //  first touch -- the paired half-block dispatches adjacently)
  floatx4 acc = {0.f, 0.f, 0.f, 0.f};
  floatx4 ha[4], hb[4];
  short8 mf[4];
#pragma unroll
  for (int j = 0; j < 4; ++j) {                 // prologue: group 0 (kb 0..3)
    ha[j] = hrow4[j * 8 + quad * 2];
    hb[j] = hrow4[j * 8 + quad * 2 + 1];
    mf[j] = *(const short8*)(mrow + j * 32);
  }
#pragma unroll
  for (int g = 0; g < 8; ++g) {
    floatx4 na[4], nb[4];
    short8 nf[4];
    if (g < 7) {
#pragma unroll
      for (int j = 0; j < 4; ++j) {             // issue next group's loads
        const int kb = (g + 1) * 4 + j;
        na[j] = hrow4[kb * 8 + quad * 2];
        nb[j] = hrow4[kb * 8 + quad * 2 + 1];
        nf[j] = *(const short8*)(mrow + kb * 32);
      }
    }
#pragma unroll
    for (int j = 0; j < 4; ++j) {               // compute current group
      short8 af;
#pragma unroll
      for (int i = 0; i < 4; ++i) { af[i] = f2bf(ha[j][i]); af[4 + i] = f2bf(hb[j][i]); }
      acc = __builtin_amdgcn_mfma_f32_16x16x32_bf16(af, mf[j], acc, 0, 0, 0);
    }
    if (g < 7) {
#pragma unroll
      for (int j = 0; j < 4; ++j) { ha[j] = na[j]; hb[j] = nb[j]; mf[j] = nf[j]; }
    }
  }

  // c: lane holds c[tok = quad*4 + i][r = m16]; add bias b[s][r]
  const float bias = bG[s * 16 + m16];
  float cf[4];
#pragma unroll
  for (int i = 0; i < 4; ++i) cf[i] = acc[i] + bias;

  // ========== transpose c -> B-frag of GEMM2-T via shuffles ==========
  // target lane L needs B[k=r=(L>>4)*8+j][n=tok=L&15] = c[tok][r];
  // source lane = (tok>>2)*16 + r, reg = tok&3.
  unsigned lo = ((unsigned)(unsigned short)f2bf(cf[0])) |
                (((unsigned)(unsigned short)f2bf(cf[1])) << 16);
  unsigned hi = ((unsigned)(unsigned short)f2bf(cf[2])) |
                (((unsigned)(unsigned short)f2bf(cf[3])) << 16);
  short8 bfrag;
  {
    const int srcbase = ((m16 >> 2) << 4) + ((quad & 1) << 3);
    const int regsel = m16 & 3;
#pragma unroll
    for (int j = 0; j < 8; ++j) {
      unsigned vlo = __shfl(lo, srcbase + j);
      unsigned vhi = __shfl(hi, srcbase + j);
      unsigned v32 = (regsel & 2) ? vhi : vlo;
      bfrag[j] = (short)((regsel & 1) ? (v32 >> 16) : (v32 & 0xffffu));
    }
  }
  const short8 zero8 = {0, 0, 0, 0, 0, 0, 0, 0};
  if (quad >= 2) bfrag = zero8;   // k = r in [16,32) is padding

  // ==== GEMM2-T + epilogue: this wave owns dt = (half*2+wvi)*16 .. +15 ===
  // A-frag: lane needs Rn^T[d = dt*16 + m16][r = q16 .. q16+7] (quads 2/3 zero)
  // D: lane holds delta[d = dt*16 + quad*4 + i][tok = m16] -> float4 epilogue
  float* orow = outG + rowoff;
  const bool valE = (tokbase + m16) < NTOK;
  const int q16 = (quad & 1) << 3;
  const short* rbase = Rg + (size_t)s * (1024 * 16) + q16;
  const int dt0 = (half * 2 + wvi) * 16;

  short8 ar[4];
  floatx4 hv[4];
#pragma unroll
  for (int j = 0; j < 4; ++j) {                 // prologue: group 0
    const int dt = dt0 + j;
    ar[j] = (quad < 2) ? *(const short8*)(rbase + (dt * 16 + m16) * 16) : zero8;
    hv[j] = *(const floatx4*)(hrow + dt * 16 + quad * 4);
  }
#pragma unroll
  for (int g = 0; g < 4; ++g) {
    short8 nr[4];
    floatx4 nh[4];
    if (g < 3) {
#pragma unroll
      for (int j = 0; j < 4; ++j) {             // issue next group's loads
        const int dt = dt0 + (g + 1) * 4 + j;
        nr[j] = (quad < 2) ? *(const short8*)(rbase + (dt * 16 + m16) * 16) : zero8;
        nh[j] = *(const floatx4*)(hrow + dt * 16 + quad * 4);
      }
    }
#pragma unroll
    for (int j = 0; j < 4; ++j) {               // compute + store current
      const int dt = dt0 + g * 4 + j;
      floatx4 z = {0.f, 0.f, 0.f, 0.f};
      floatx4 dv = __builtin_amdgcn_mfma_f32_16x16x32_bf16(ar[j], bfrag, z, 0, 0, 0);
      if (valE) {
        floatx4 o;
#pragma unroll
        for (int i = 0; i < 4; ++i) o[i] = hv[j][i] + dv[i];
        *(floatx4*)(orow + dt * 16 + quad * 4) = o;
      }
    }
    if (g < 3) {
#pragma unroll
      for (int j = 0; j < 4; ++j) { ar[j] = nr[j]; hv[j] = nh[j]; }
    }
  }
}

extern "C" void kernel_launch(void* const* d_in, const int* in_sizes, int n_in,
                              void* d_out, int out_size, void* d_ws, size_t ws_size,
                              hipStream_t stream) {
  const float* h = (const float*)d_in[0];
  const float* R = (const float*)d_in[1];
  const float* W = (const float*)d_in[2];
  const float* b = (const float*)d_in[3];
  // workspace: Mg (50*16*1024 bf16 = 1.64 MB) then Rg (same) = 3.28 MB total
  short* Mg = (short*)d_ws;
  short* Rg = Mg + (size_t)S_ * 16 * 1024;
  loreft_prep<<<dim3(S_), 256, 0, stream>>>(R, W, Mg, Rg);
  loreft_main<<<dim3(78, S_), 128, 0, stream>>>(h, b, Mg, Rg, (float*)d_out);
}

// Round 6
// 263.234 us; speedup vs baseline: 1.1867x; 1.1867x over previous
//
#include <hip/hip_runtime.h>

// StepConditionalLoReFT: out = h + Rn^T (W h + b - Rn h) per step s.
// All tensors FP32 (per reference). B=8 S=50 T=77 D=1024 r=16.
//
// Two kernels:
//  1) loreft_prep (50 blocks): Rn = R/max(||R||,eps), M = W - Rn -> bf16 in
//     workspace: Mg[s][r][d] (GEMM1 B-frag order), Rg[s][d][r] (GEMM2 A-frag
//     order). 3.3 MB total -> L2-resident for the main kernel.
//  2) loreft_main (grid 39 x 50, 256 thr = 4 waves, 64 KB LDS):
//     h 16-token tile staged ONCE into LDS via async global_load_lds
//     (16 KB in flight per wave -- VGPR-free, compiler cannot sink it;
//     fixes the round-1/2/5 finding that reg-staged pipelines compile to
//     VGPR=52 with ~no loads in flight, capping fabric rate at ~2.4 TB/s).
//     GEMM1 A-frags AND the epilogue h read come from LDS -> h is fetched
//     from HBM exactly once (kills round-5's 219 MB FETCH and the epilogue
//     re-read). LDS is XOR-swizzled (16B-block ^ (row&7)) via PRE-SWIZZLED
//     GLOBAL source addresses (linear LDS dest, swizzled ds_read) ->
//     conflict-free GEMM1 and epilogue reads.

typedef __attribute__((ext_vector_type(8))) short short8;
typedef __attribute__((ext_vector_type(4))) float floatx4;

__device__ __forceinline__ short f2bf(float f) {
  unsigned u = __float_as_uint(f);
  u += 0x7fffu + ((u >> 16) & 1u);   // round-to-nearest-even
  return (short)(u >> 16);
}

#define S_ 50
#define T_ 77
#define NTOK 616   // B*T tokens per step s

// ================= prep kernel =================
__global__ __launch_bounds__(256) void loreft_prep(
    const float* __restrict__ RG, const float* __restrict__ WG,
    short* __restrict__ Mg, short* __restrict__ Rg) {
  __shared__ float RnL[16][1024];
  const int s = blockIdx.x;
  const int tid = threadIdx.x;
  const int lane = tid & 63;
  const int wvi = tid >> 6;

#pragma unroll
  for (int rr = 0; rr < 4; ++rr) {
    const int r = wvi * 4 + rr;
    const floatx4* Rrow = (const floatx4*)(RG + (size_t)((s * 16 + r) << 10));
    const floatx4* Wrow = (const floatx4*)(WG + (size_t)((s * 16 + r) << 10));
    floatx4 rv0 = Rrow[lane * 4 + 0];
    floatx4 rv1 = Rrow[lane * 4 + 1];
    floatx4 rv2 = Rrow[lane * 4 + 2];
    floatx4 rv3 = Rrow[lane * 4 + 3];
    float ss = 0.f;
#pragma unroll
    for (int j = 0; j < 4; ++j)
      ss += rv0[j] * rv0[j] + rv1[j] * rv1[j] + rv2[j] * rv2[j] + rv3[j] * rv3[j];
#pragma unroll
    for (int m = 1; m < 64; m <<= 1) ss += __shfl_xor(ss, m);
    const float inv = 1.0f / fmaxf(sqrtf(ss), 1e-12f);

    floatx4 wa0 = Wrow[lane * 4 + 0];
    floatx4 wa1 = Wrow[lane * 4 + 1];
    floatx4 wa2 = Wrow[lane * 4 + 2];
    floatx4 wa3 = Wrow[lane * 4 + 3];
    float rn[16];
    short8 m0, m1;
#pragma unroll
    for (int j = 0; j < 4; ++j) {
      rn[j]      = rv0[j] * inv;  m0[j]     = f2bf(wa0[j] - rn[j]);
      rn[4 + j]  = rv1[j] * inv;  m0[4 + j] = f2bf(wa1[j] - rn[4 + j]);
      rn[8 + j]  = rv2[j] * inv;  m1[j]     = f2bf(wa2[j] - rn[8 + j]);
      rn[12 + j] = rv3[j] * inv;  m1[4 + j] = f2bf(wa3[j] - rn[12 + j]);
    }
    // Mg[s][r][d] row-major bf16, lane covers d = lane*16 .. +15
    short* mdst = Mg + (size_t)(s * 16 + r) * 1024 + lane * 16;
    *(short8*)mdst = m0;
    *(short8*)(mdst + 8) = m1;
#pragma unroll
    for (int jj = 0; jj < 16; ++jj) RnL[r][lane * 16 + jj] = rn[jj];
  }
  __syncthreads();

  // Rg[s][d][r]: thread handles d = dd*256 + tid, writes 16 r-values (32 B)
#pragma unroll
  for (int dd = 0; dd < 4; ++dd) {
    const int d = dd * 256 + tid;
    short8 lo8, hi8;
#pragma unroll
    for (int rj = 0; rj < 8; ++rj) {
      lo8[rj] = f2bf(RnL[rj][d]);
      hi8[rj] = f2bf(RnL[rj + 8][d]);
    }
    short* dst = Rg + ((size_t)s * 1024 + d) * 16;
    *(short8*)dst = lo8;
    *(short8*)(dst + 8) = hi8;
  }
}

// ===== main kernel: async LDS-staged h tile, 4 waves, one barrier =========
__global__ __launch_bounds__(256, 2) void loreft_main(
    const float* __restrict__ hG, const float* __restrict__ bG,
    const short* __restrict__ Mg, const short* __restrict__ Rg,
    float* __restrict__ outG) {
  // h tile: 16 rows x 1024 f32 = 64 KB. 16B-block b of row r stored at
  // physical block (b ^ (r&7)) -> conflict-free ds_read in GEMM1 + epilogue.
  __shared__ float hT[16 * 1024];

  const int tid = threadIdx.x;
  const int lane = tid & 63;
  const int wvi = tid >> 6;       // wave 0..3
  const int m16 = lane & 15;
  const int quad = lane >> 4;
  const int tile = blockIdx.x;    // 39 tiles cover 616 tokens
  const int s = blockIdx.y;
  const int tokbase = tile * 16;

  // ---------- async stage: wave wvi loads rows wvi*4 .. +3 ----------
  // LDS dest is linear (HW: uniform base + lane*16); the XOR swizzle is
  // applied on the GLOBAL source address (both-sides rule).
#pragma unroll
  for (int rr = 0; rr < 4; ++rr) {
    const int rloc = wvi * 4 + rr;
    int tok = tokbase + rloc; if (tok > NTOK - 1) tok = NTOK - 1;
    const int bb = tok / T_;
    const int tt = tok - bb * T_;
    const float* rsrc = hG + (((size_t)((bb * S_ + s) * T_ + tt)) << 10);
    const int rsw = rloc & 7;
    const int lsw = lane ^ rsw;   // permutes within 128B groups: coalesced
#pragma unroll
    for (int g = 0; g < 4; ++g) {
      const float* gsrc = rsrc + ((g * 64 + lsw) << 2);
      __builtin_amdgcn_global_load_lds(
          (const __attribute__((address_space(1))) void*)gsrc,
          (__attribute__((address_space(3))) void*)&hT[rloc * 1024 + g * 256],
          16, 0, 0);
    }
  }

  // per-lane row offset for the C store (and its clamp), while loads fly
  int tokA = tokbase + m16; if (tokA > NTOK - 1) tokA = NTOK - 1;
  const int bb1 = tokA / T_;
  const int tt1 = tokA - bb1 * T_;
  const size_t rowoff = ((size_t)((bb1 * S_ + s) * T_ + tt1)) << 10;
  // GEMM1 B-frag: lane (quad,m16) needs M[r=m16][k = kb*32 + quad*8 + j]
  const short* mrow = Mg + (size_t)(s * 16 + m16) * 1024 + quad * 8;
  const float bias = bG[s * 16 + m16];
  const int sw = m16 & 7;
  const float* hls = &hT[m16 * 1024];   // this lane's h row in LDS

  __syncthreads();   // drains vmcnt(0): staging complete

  // ---------- GEMM1: c[tok, r] = H M^T (A-frags from LDS) ----------
  floatx4 acc = {0.f, 0.f, 0.f, 0.f};
#pragma unroll
  for (int kg = 0; kg < 4; ++kg) {
    short8 mf[8];
#pragma unroll
    for (int j = 0; j < 8; ++j)          // 8 independent L2 loads, issued together
      mf[j] = *(const short8*)(mrow + (kg * 8 + j) * 32);
#pragma unroll
    for (int j = 0; j < 8; ++j) {
      const int kb = kg * 8 + j;
      const int blk = kb * 8 + quad * 2;
      floatx4 p0 = *(const floatx4*)(hls + (((blk) ^ sw) << 2));
      floatx4 p1 = *(const floatx4*)(hls + (((blk + 1) ^ sw) << 2));
      short8 af;
#pragma unroll
      for (int i = 0; i < 4; ++i) { af[i] = f2bf(p0[i]); af[4 + i] = f2bf(p1[i]); }
      acc = __builtin_amdgcn_mfma_f32_16x16x32_bf16(af, mf[j], acc, 0, 0, 0);
    }
  }

  // c: lane holds c[tok = quad*4 + i][r = m16]; add bias b[s][r]
  float cf[4];
#pragma unroll
  for (int i = 0; i < 4; ++i) cf[i] = acc[i] + bias;

  // ========== transpose c -> B-frag of GEMM2-T via shuffles ==========
  // target lane L needs B[k=r=(L>>4)*8+j][n=tok=L&15] = c[tok][r];
  // source lane = (tok>>2)*16 + r, reg = tok&3.
  unsigned lo = ((unsigned)(unsigned short)f2bf(cf[0])) |
                (((unsigned)(unsigned short)f2bf(cf[1])) << 16);
  unsigned hi = ((unsigned)(unsigned short)f2bf(cf[2])) |
                (((unsigned)(unsigned short)f2bf(cf[3])) << 16);
  short8 bfrag;
  {
    const int srcbase = ((m16 >> 2) << 4) + ((quad & 1) << 3);
    const int regsel = m16 & 3;
#pragma unroll
    for (int j = 0; j < 8; ++j) {
      unsigned vlo = __shfl(lo, srcbase + j);
      unsigned vhi = __shfl(hi, srcbase + j);
      unsigned v32 = (regsel & 2) ? vhi : vlo;
      bfrag[j] = (short)((regsel & 1) ? (v32 >> 16) : (v32 & 0xffffu));
    }
  }
  const short8 zero8 = {0, 0, 0, 0, 0, 0, 0, 0};
  if (quad >= 2) bfrag = zero8;   // k = r in [16,32) is padding

  // ========== GEMM2-T + epilogue: this wave owns dt = wvi*16 .. +15 ======
  // A-frag: lane needs Rn^T[d = dt*16 + m16][r = q16 .. q16+7] (quads 2/3 zero)
  // D: lane holds delta[d = dt*16 + quad*4 + i][tok = m16]; h from LDS.
  float* orow = outG + rowoff;
  const bool valE = (tokbase + m16) < NTOK;
  const int q16 = (quad & 1) << 3;
  const short* rbase = Rg + (size_t)s * (1024 * 16) + q16;
  const int dt0 = wvi * 16;

  short8 ar[4];
#pragma unroll
  for (int j = 0; j < 4; ++j) {                 // prologue: group 0 Rg frags
    const int dt = dt0 + j;
    ar[j] = (quad < 2) ? *(const short8*)(rbase + (dt * 16 + m16) * 16) : zero8;
  }
#pragma unroll
  for (int g = 0; g < 4; ++g) {
    short8 nr[4];
    if (g < 3) {
#pragma unroll
      for (int j = 0; j < 4; ++j) {             // issue next group's Rg loads
        const int dt = dt0 + (g + 1) * 4 + j;
        nr[j] = (quad < 2) ? *(const short8*)(rbase + (dt * 16 + m16) * 16) : zero8;
      }
    }
#pragma unroll
    for (int j = 0; j < 4; ++j) {               // compute + store current
      const int dt = dt0 + g * 4 + j;
      floatx4 z = {0.f, 0.f, 0.f, 0.f};
      floatx4 dv = __builtin_amdgcn_mfma_f32_16x16x32_bf16(ar[j], bfrag, z, 0, 0, 0);
      // h for this lane's (d, tok=m16) from LDS: block dt*4+quad of row m16
      floatx4 hv = *(const floatx4*)(&hT[m16 * 1024 + (((dt * 4 + quad) ^ sw) << 2)]);
      if (valE) {
        floatx4 o;
#pragma unroll
        for (int i = 0; i < 4; ++i) o[i] = hv[i] + dv[i];
        *(floatx4*)(orow + dt * 16 + quad * 4) = o;
      }
    }
    if (g < 3) {
#pragma unroll
      for (int j = 0; j < 4; ++j) ar[j] = nr[j];
    }
  }
}

extern "C" void kernel_launch(void* const* d_in, const int* in_sizes, int n_in,
                              void* d_out, int out_size, void* d_ws, size_t ws_size,
                              hipStream_t stream) {
  const float* h = (const float*)d_in[0];
  const float* R = (const float*)d_in[1];
  const float* W = (const float*)d_in[2];
  const float* b = (const float*)d_in[3];
  // workspace: Mg (50*16*1024 bf16 = 1.64 MB) then Rg (same) = 3.28 MB total
  short* Mg = (short*)d_ws;
  short* Rg = Mg + (size_t)S_ * 16 * 1024;
  loreft_prep<<<dim3(S_), 256, 0, stream>>>(R, W, Mg, Rg);
  loreft_main<<<dim3(39, S_), 256, 0, stream>>>(h, b, Mg, Rg, (float*)d_out);
}